// Round 10
// baseline (164.693 us; speedup 1.0000x reference)
//
#include <hip/hip_runtime.h>
#include <hip/hip_bf16.h>
#include <math.h>

#define NEGV (-1e10f)

typedef __attribute__((ext_vector_type(8))) short bf16x8;
typedef __attribute__((ext_vector_type(4))) float f32x4;
typedef __attribute__((ext_vector_type(16))) float f32x16;

static __device__ __forceinline__ unsigned short f2bf(float f) {
  unsigned int u = __builtin_bit_cast(unsigned int, f);
  unsigned int r = (u + 0x7fffu + ((u >> 16) & 1u)) >> 16;
  return (unsigned short)r;
}
static __device__ __forceinline__ float bf2f(unsigned short v) {
  return __builtin_bit_cast(float, (unsigned int)v << 16);
}
// RNE pack of two f32 -> two bf16 in one u32 (identical rounding to f2bf)
static __device__ __forceinline__ unsigned int pkbf(float lo, float hi) {
  unsigned int r;
  asm("v_cvt_pk_bf16_f32 %0, %1, %2" : "=v"(r) : "v"(lo), "v"(hi));
  return r;
}

#define GLD16(g, l)                                                   \
  __builtin_amdgcn_global_load_lds(                                   \
      (const __attribute__((address_space(1))) void*)(g),             \
      (__attribute__((address_space(3))) void*)(l), 16, 0, 0)

// lgkm-only barrier: does NOT drain vmcnt (keeps staged loads in flight;
// __syncthreads would emit s_waitcnt vmcnt(0) and kill the pipeline)
#define LBAR()                                                  \
  do {                                                          \
    asm volatile("s_waitcnt lgkmcnt(0)" ::: "memory");          \
    __builtin_amdgcn_s_barrier();                               \
  } while (0)

// ---------------------------------------------------------------------------
// K1: merged input casts + out-zeroing (replaces hipMemsetAsync launch).
// Blocks [0,2048): emb fp32->bf16 + attn-weight logits. Blocks [2048,3776):
// weight matrices fp32->bf16; W_q is PRE-SCALED by C2 = log2e/sqrt(96) in
// fp32 (folds the attn softmax scale into the GEMM; QK^T then feeds exp2
// directly). W_q/W_k rows are PERMUTED (same perm on both -> QK^T invariant).
// ---------------------------------------------------------------------------
__global__ __launch_bounds__(256) void cast_inputs(
    const float* __restrict__ emb, const int* __restrict__ tags,
    const float* __restrict__ ww, const float* __restrict__ wq,
    const float* __restrict__ wk, const float* __restrict__ wv,
    unsigned short* __restrict__ embbf, float* __restrict__ logits,
    unsigned short* __restrict__ wbf, float* __restrict__ out) {
  int bx = blockIdx.x;
  if (bx < 2048) {
    int w = threadIdx.x >> 6, lane = threadIdx.x & 63;
    int row = bx * 4 + w;  // 0..8191
    const float4* src = (const float4*)(emb + (size_t)row * 768);
    const float4* wsrc = (const float4*)ww;
    uint2* dst = (uint2*)(embbf + (size_t)row * 768);
    float d = 0.f;
#pragma unroll
    for (int j = 0; j < 3; j++) {
      int idx = lane + 64 * j;
      float4 v = src[idx];
      float4 wv = wsrc[idx];
      d += v.x * wv.x + v.y * wv.y + v.z * wv.z + v.w * wv.w;
      uint2 o;
      o.x = pkbf(v.x, v.y);
      o.y = pkbf(v.z, v.w);
      dst[idx] = o;
    }
#pragma unroll
    for (int off = 32; off; off >>= 1) d += __shfl_xor(d, off);
    if (lane == 0) logits[row] = (tags[row] == 0) ? NEGV : d;
  } else {
    int g = bx - 2048;              // 0..1727
    int z = g / 576;                // matrix
    int idx = (g - z * 576) * 256 + threadIdx.x;  // float4 index
    const float* src = (z == 0) ? wq : (z == 1) ? wk : wv;
    float4 v = ((const float4*)src)[idx];
    if (z == 0) {  // fold softmax scale into W_q (fp32, before bf16 round)
      const float C2 = 0.10206207261596577f * 1.4426950408889634f;
      v.x *= C2; v.y *= C2; v.z *= C2; v.w *= C2;
    }
    uint2 o;
    o.x = pkbf(v.x, v.y);
    o.y = pkbf(v.z, v.w);
    uint2* W2 = (uint2*)(wbf + (size_t)z * 589824);
    if (z == 2) {
      W2[idx] = o;
    } else {
      int f = idx / 192;            // source feature row
      int col4 = idx - f * 192;
      int h = f & 7, dg = f >> 3;   // head, depth 0..95
      int tt = dg >> 4, ddl = dg & 15;
      int wn = ddl >> 3, cb = (ddl >> 2) & 1, j = ddl & 3;
      int orow = tt * 128 + wn * 64 + j * 16 + cb * 8 + h;
      W2[orow * 192 + col4] = o;
    }
    if (bx == 3775) {  // zero `out` (8x768 f32 = 1536 float4); stream order
      float4 z4 = {0.f, 0.f, 0.f, 0.f};  // guarantees this precedes finalize
#pragma unroll
      for (int q = 0; q < 6; q++) ((float4*)out)[q * 256 + threadIdx.x] = z4;
    }
  }
}

// ---------------------------------------------------------------------------
// K3: QKV projection GEMM, v6 (R7-verified): XCD-chunked block remap (T1),
// 3-buffer LDS ring, depth-2 prefetch, counted vmcnt(4)+raw barrier,
// conflict-free fragment swizzle. Grid LINEAR 1152 = 8 XCDs x 144;
// xcd = g&7 owns mb-panels [xcd*8, xcd*8+8) == batch xcd -> A-panels (1.5MB)
// + one B matrix (1.18MB) L2-resident per XCD. See R3/R5/R6 comments.
// ---------------------------------------------------------------------------
__global__ __launch_bounds__(256, 3) void qkv_gemm(
    const unsigned short* __restrict__ A, const unsigned short* __restrict__ Wbf,
    unsigned short* __restrict__ Qf, unsigned short* __restrict__ Kf,
    unsigned short* __restrict__ Vbf) {
  __shared__ __align__(16) unsigned short sm[24576];  // ring: 3 x 8192 shorts
  int g = blockIdx.x;          // 0..1151
  int xcd = g & 7, local = g >> 3;
  int mbi = xcd * 8 + (local & 7);  // 0..63
  int nbz = local >> 3;             // 0..17
  int z = nbz / 6;
  int nbi = nbz - z * 6;            // 0..5
  const unsigned short* B = Wbf + (size_t)z * 589824;
  int mb = mbi * 128, nb = nbi * 128;
  int tid = threadIdx.x;
  int w = tid >> 6, lane = tid & 63;
  int wm = w >> 1, wn = w & 1;
  int c = lane & 15, quad = lane >> 4;
  int lrow = lane >> 2;
  int lcol = ((lane & 3) ^ ((lrow >> 1) & 3)) * 8;  // bank-spread source chunk
  const unsigned short* Ag = A + (size_t)(mb + w * 32 + lrow) * 768 + lcol;
  const unsigned short* Bg = B + (size_t)(nb + w * 32 + lrow) * 768 + lcol;
  int woff = w * 1024;

  // One K-tile stage: A -> slot base, B -> slot base + 4096 (shorts)
#define PREFETCH(buf, kb)                                                   \
  do {                                                                      \
    GLD16(Ag + (kb), sm + (buf) * 8192 + woff);                             \
    GLD16(Ag + (kb) + 16 * 768, sm + (buf) * 8192 + woff + 512);            \
    GLD16(Bg + (kb), sm + (buf) * 8192 + 4096 + woff);                      \
    GLD16(Bg + (kb) + 16 * 768, sm + (buf) * 8192 + 4096 + woff + 512);     \
  } while (0)

  f32x4 acc[4][4];
#pragma unroll
  for (int i = 0; i < 4; i++)
#pragma unroll
    for (int j = 0; j < 4; j++) acc[i][j] = 0;

  PREFETCH(0, 0);
  PREFETCH(1, 32);

  int rd = 0;
  int sw = (quad ^ ((c >> 1) & 3)) * 8;  // conflict-free swizzled chunk
  for (int it = 0; it < 24; it++) {
    if (it < 23) {
      asm volatile("s_waitcnt vmcnt(4) lgkmcnt(0)" ::: "memory");
    } else {
      asm volatile("s_waitcnt vmcnt(0) lgkmcnt(0)" ::: "memory");
    }
    __builtin_amdgcn_s_barrier();
    if (it + 2 < 24) {
      int wr = rd + 2;
      if (wr >= 3) wr -= 3;
      PREFETCH(wr, (it + 2) * 32);
    }
    const unsigned short* Ab = sm + rd * 8192;
    const unsigned short* Bb = Ab + 4096;
    bf16x8 af[4], bfr[4];
#pragma unroll
    for (int i = 0; i < 4; i++)
      af[i] = *(const bf16x8*)&Ab[(wm * 64 + i * 16 + c) * 32 + sw];
#pragma unroll
    for (int j = 0; j < 4; j++)
      bfr[j] = *(const bf16x8*)&Bb[(wn * 64 + j * 16 + c) * 32 + sw];
#pragma unroll
    for (int i = 0; i < 4; i++)
#pragma unroll
      for (int j = 0; j < 4; j++)
        acc[i][j] = __builtin_amdgcn_mfma_f32_16x16x32_bf16(af[i], bfr[j],
                                                            acc[i][j], 0, 0, 0);
    rd = (rd == 2) ? 0 : rd + 1;
  }
  __syncthreads();  // all staging/reads done before epilogue reuses sm

  // C row = mb+wm*64+i*16+quad*4+r, col = nb+wn*64+j*16+c
  if (z == 2) {
#pragma unroll
    for (int i = 0; i < 4; i++)
#pragma unroll
      for (int j = 0; j < 4; j++)
#pragma unroll
        for (int r = 0; r < 4; r++) {
          int rl = wm * 64 + i * 16 + quad * 4 + r;
          int cl = wn * 64 + j * 16 + c;
          sm[rl * 136 + cl] = f2bf(acc[i][j][r]);
        }
    __syncthreads();
#pragma unroll
    for (int it2 = 0; it2 < 8; it2++) {
      int g2 = it2 * 256 + tid;  // 0..2047, 16B units (128 rows x 16)
      int rl = g2 >> 4;
      int cu = (g2 & 15) * 8;
      bf16x8 vdat = *(const bf16x8*)&sm[rl * 136 + cu];
      *(bf16x8*)&Vbf[(size_t)(mb + rl) * 768 + nb + cu] = vdat;
    }
  } else {
    unsigned short* O = (z == 0) ? Qf : Kf;
#pragma unroll
    for (int i = 0; i < 4; i++) {
#pragma unroll
      for (int r = 0; r < 4; r++) {
        int qlr = wm * 64 + i * 16 + quad * 4 + r;  // 0..127
        int chunkL = (qlr >> 5) * 8 + (c & 7);      // 0..31
        int lane32 = (qlr & 31) + wn * 32;
        uint2 o;
        o.x = pkbf(acc[i][0][r], acc[i][1][r]);
        o.y = pkbf(acc[i][2][r], acc[i][3][r]);
        *(uint2*)&sm[chunkL * 520 + lane32 * 8 + 4 * (c >> 3)] = o;
      }
    }
    __syncthreads();
    int bq = mb >> 10;
    int qt32g0 = (mb & 1023) >> 5;
    int tt = nbi;  // d/16 chunk (0..5)
#pragma unroll
    for (int it2 = 0; it2 < 8; it2++) {
      int gg = it2 * 256 + tid;
      int chunkL = gg >> 6;
      int off = (gg & 63) * 8;
      bf16x8 vdat = *(const bf16x8*)&sm[chunkL * 520 + off];
      int qt32 = qt32g0 + (chunkL >> 3), h = chunkL & 7;
      size_t dst = ((((size_t)(bq * 32 + qt32) * 8 + h) * 6 + tt) << 9) + off;
      *(bf16x8*)&O[dst] = vdat;
    }
  }
#undef PREFETCH
}

// ---------------------------------------------------------------------------
// K4: attention v3 -- h-phase LDS staging with qkv's PROVEN ring discipline.
// Why: R7 counters showed attn is L2-BW-bound: each wave loaded its own
// 96KB of Q+K (wave pairs read IDENTICAL data) -> 384KB/block, 786MB L2
// traffic total (~6.4K cyc/block at 60B/cyc/CU ~= the measured idle).
// Staging dedups pairs: 192KB/block. R6's staged attempt lost because it
// used depth-1 + vmcnt(0)-drain per phase (the m218 "drain0" anti-pattern);
// this version uses ring-3 + depth-2 prefetch + counted vmcnt(6) + raw
// barriers (exact qkv R3 ledger: 6 loads/thread/phase; at phase h the queue
// is stage(h)x6 + stage(h+1)x6 -> vmcnt(6) drains h, keeps h+1 in flight;
// drain-to-0 only at h=7). Inline aw-softmax prologue runs UNDER stage(0/1)
// flight using lgkm-only raw barriers (LBAR; __syncthreads would emit
// vmcnt(0) and drain the pipe). logits loads are issued BEFORE the stages
// so their waits leave the stage queue intact (LLVM's waitcnt pass counts
// global_load_lds in the same vmcnt queue -> x0..x3 use waits at ~vmcnt(12)).
// WAR ledger: stage(h+2) writes slot (h+2)%3, last read at phase h-1, whose
// ds_reads are drained by that wave's lgkmcnt(0) before barrier B_h; stage
// issues after B_h. All barriers on block-uniform paths (no deadlock).
// Numerics/layout identical to R6 (passed) + R8 (pre-scaled W_q, exp2).
// Grid: 2048 linear; b = id&7 pins batch b to XCD b (qkv wrote it there).
// ---------------------------------------------------------------------------
__global__ __launch_bounds__(256) void attn(
    const unsigned short* __restrict__ Qf, const unsigned short* __restrict__ Kf,
    const float* __restrict__ logits, float* __restrict__ Ptp) {
  __shared__ __align__(16) unsigned short kv[36864];  // ring: 3 x 12288 shorts
  __shared__ float pbuf[1024];  // aw[q]; later partial sums
  __shared__ float red[4];
  int id = blockIdx.x;
  int b = id & 7, qb = (id >> 3) & 15, kb = id >> 7;
  int tid = threadIdx.x, w = tid >> 6, lane = tid & 63;
  int wq = w >> 1, wk = w & 1;

  // logits loads FIRST (oldest in vmcnt queue; their waits don't drain stages)
  const float* L = logits + b * 1024;
  float x0 = L[tid], x1 = L[tid + 256], x2 = L[tid + 512], x3 = L[tid + 768];

  // Staging plan: 24 chunks of 512 shorts (1KB): c = part*12 + qt*6 + t.
  const unsigned short* srcp[6];
  int dsto[6];
#pragma unroll
  for (int l6 = 0; l6 < 6; l6++) {
    int cch = l6 * 4 + w;            // 0..23
    int part = (cch >= 12) ? 1 : 0;  // 0 = Q, 1 = K
    int r = cch - part * 12;
    int qt = r / 6, t = r - qt * 6;
    const unsigned short* base = part ? Kf : Qf;
    int tb = part ? kb : qb;
    srcp[l6] = base + ((size_t)((b * 32 + tb * 2 + qt) * 8) * 6 + t) * 512 +
               lane * 8;
    dsto[l6] = cch * 512 + lane * 8;
  }

#define STAGE(slot, hh)                                          \
  do {                                                           \
    GLD16(srcp[0] + (hh) * 3072, kv + (slot) * 12288 + dsto[0]); \
    GLD16(srcp[1] + (hh) * 3072, kv + (slot) * 12288 + dsto[1]); \
    GLD16(srcp[2] + (hh) * 3072, kv + (slot) * 12288 + dsto[2]); \
    GLD16(srcp[3] + (hh) * 3072, kv + (slot) * 12288 + dsto[3]); \
    GLD16(srcp[4] + (hh) * 3072, kv + (slot) * 12288 + dsto[4]); \
    GLD16(srcp[5] + (hh) * 3072, kv + (slot) * 12288 + dsto[5]); \
  } while (0)

  STAGE(0, 0);
  STAGE(1, 1);

  {  // inline softmax of masked logits -> pbuf[q] = aw (hides stage latency)
    float m = fmaxf(fmaxf(x0, x1), fmaxf(x2, x3));
#pragma unroll
    for (int off = 32; off; off >>= 1) m = fmaxf(m, __shfl_xor(m, off));
    if ((tid & 63) == 0) red[tid >> 6] = m;
    LBAR();
    m = fmaxf(fmaxf(red[0], red[1]), fmaxf(red[2], red[3]));
    float e0 = __expf(x0 - m), e1 = __expf(x1 - m), e2 = __expf(x2 - m),
          e3 = __expf(x3 - m);
    float s = e0 + e1 + e2 + e3;
#pragma unroll
    for (int off = 32; off; off >>= 1) s += __shfl_xor(s, off);
    LBAR();  // red WAR guard
    if ((tid & 63) == 0) red[tid >> 6] = s;
    LBAR();
    float inv = 1.0f / (red[0] + red[1] + red[2] + red[3]);
    pbuf[tid] = e0 * inv;
    pbuf[tid + 256] = e1 * inv;
    pbuf[tid + 512] = e2 * inv;
    pbuf[tid + 768] = e3 * inv;
    // visibility of pbuf to other waves is covered by the loop barriers
  }

  f32x16 acc[8];
#pragma unroll
  for (int h = 0; h < 8; h++) acc[h] = 0;

  int rd = 0;
#pragma unroll
  for (int h = 0; h < 8; h++) {
    if (h < 7) {
      asm volatile("s_waitcnt vmcnt(6) lgkmcnt(0)" ::: "memory");
    } else {
      asm volatile("s_waitcnt vmcnt(0) lgkmcnt(0)" ::: "memory");
    }
    __builtin_amdgcn_s_barrier();
    if (h + 2 < 8) {
      int wr = rd + 2;
      if (wr >= 3) wr -= 3;
      STAGE(wr, h + 2);
    }
    const unsigned short* Qs = kv + rd * 12288 + wq * 3072 + lane * 8;
    const unsigned short* Ks = kv + rd * 12288 + 6144 + wk * 3072 + lane * 8;
#pragma unroll
    for (int t = 0; t < 6; t++) {
      bf16x8 a = *(const bf16x8*)(Qs + t * 512);
      bf16x8 bb = *(const bf16x8*)(Ks + t * 512);
      acc[h] = __builtin_amdgcn_mfma_f32_32x32x16_bf16(a, bb, acc[h], 0, 0, 0);
    }
    rd = (rd == 2) ? 0 : rd + 1;
  }
#undef STAGE

  // softmax over h per (q,k); C/D: col=lane&31 (k), row=(reg&3)+8*(reg>>2)+4*(lane>>5)
  float awv[16];
#pragma unroll
  for (int reg = 0; reg < 16; reg++) {
    int row = (reg & 3) + 8 * (reg >> 2) + 4 * (lane >> 5);
    awv[reg] = pbuf[qb * 64 + wq * 32 + row];
  }
  __syncthreads();  // all aw reads done before pbuf is overwritten below
  float partial[8];
#pragma unroll
  for (int h = 0; h < 8; h++) partial[h] = 0.f;
#pragma unroll
  for (int reg = 0; reg < 16; reg++) {
    float v[8];
    float ssum = 0.f;
#pragma unroll
    for (int h = 0; h < 8; h++) {
      float e = exp2f(acc[h][reg]);  // scale pre-folded into W_q
      v[h] = e;
      ssum += e;
    }
    float g = awv[reg] * __builtin_amdgcn_rcpf(ssum);  // aw==0 for padded q
#pragma unroll
    for (int h = 0; h < 8; h++) partial[h] += v[h] * g;
  }
#pragma unroll
  for (int h = 0; h < 8; h++) {
    float v = partial[h];
    v += __shfl_xor(v, 32);  // combine row halves -> full 32-q sum per col
    partial[h] = v;
  }
  if (lane < 32) {
#pragma unroll
    for (int h = 0; h < 8; h++) pbuf[w * 256 + lane * 8 + h] = partial[h];
  }
  __syncthreads();
  // 256 threads each write BOTH wk halves (512 outputs total)
#pragma unroll
  for (int wk2 = 0; wk2 < 2; wk2++) {
    float s = pbuf[wk2 * 256 + tid] + pbuf[(2 + wk2) * 256 + tid];
    int kcol = tid >> 3, h = tid & 7;
    Ptp[(((size_t)qb * 8 + b) * 1024 + kb * 64 + wk2 * 32 + kcol) * 8 + h] = s;
  }
}

// ---------------------------------------------------------------------------
// K5: out[b,o] = sum_k (sum_qb Ptp[qb][b][k][o&7]) * V[b,k,o]   (V bf16)
// grid (32 kc, 8 b); threads 0..191 each own 4 consecutive o (ushort4 loads)
// out zeroed by cast_inputs (stream-ordered).
// ---------------------------------------------------------------------------
__global__ __launch_bounds__(256) void finalize(
    const float* __restrict__ Ptp, const unsigned short* __restrict__ Vbf,
    float* __restrict__ out) {
  __shared__ float ps[256];  // 32 k x 8 h
  int kc = blockIdx.x, b = blockIdx.y;
  int t = threadIdx.x;
  {
    int k = kc * 32 + (t >> 3), h = t & 7;
    float s = 0.f;
#pragma unroll
    for (int qc = 0; qc < 16; qc++)
      s += Ptp[(((size_t)qc * 8 + b) * 1024 + k) * 8 + h];
    ps[t] = s;
  }
  __syncthreads();
  if (t < 192) {
    int o0 = t * 4;
    int hb = o0 & 7;  // 0 or 4
    float a0 = 0, a1 = 0, a2 = 0, a3 = 0;
    const unsigned short* Vb = Vbf + ((size_t)b * 1024 + kc * 32) * 768 + o0;
#pragma unroll 4
    for (int kk = 0; kk < 32; kk++) {
      ushort4 vv = *(const ushort4*)(Vb + (size_t)kk * 768);
      const float* p = &ps[kk * 8 + hb];
      a0 += p[0] * bf2f(vv.x);
      a1 += p[1] * bf2f(vv.y);
      a2 += p[2] * bf2f(vv.z);
      a3 += p[3] * bf2f(vv.w);
    }
    atomicAdd(&out[b * 768 + o0], a0);
    atomicAdd(&out[b * 768 + o0 + 1], a1);
    atomicAdd(&out[b * 768 + o0 + 2], a2);
    atomicAdd(&out[b * 768 + o0 + 3], a3);
  }
}

// ---------------------------------------------------------------------------
extern "C" void kernel_launch(void* const* d_in, const int* in_sizes, int n_in,
                              void* d_out, int out_size, void* d_ws,
                              size_t ws_size, hipStream_t stream) {
  const float* emb = (const float*)d_in[0];
  const int* tags = (const int*)d_in[1];
  const float* ww = (const float*)d_in[2];
  const float* wq = (const float*)d_in[3];
  const float* wk = (const float*)d_in[4];
  const float* wv = (const float*)d_in[5];
  float* out = (float*)d_out;
  char* ws = (char*)d_ws;
  unsigned short* embbf = (unsigned short*)(ws + 0);           // 12,582,912
  unsigned short* wbf   = (unsigned short*)(ws + 12582912);    //  3,538,944
  unsigned short* Qf    = (unsigned short*)(ws + 16121856);    // 12,582,912
  unsigned short* Kf    = (unsigned short*)(ws + 28704768);    // 12,582,912
  unsigned short* Vbf   = (unsigned short*)(ws + 41287680);    // 12,582,912
  float* logits         = (float*)(ws + 53870592);             //     32,768
  float* Ptp            = (float*)(ws + 53936128);             //  4,194,304

  cast_inputs<<<3776, 256, 0, stream>>>(emb, tags, ww, wq, wk, wv, embbf,
                                        logits, wbf, out);
  qkv_gemm<<<1152, 256, 0, stream>>>(embbf, wbf, Qf, Kf, Vbf);
  attn<<<2048, 256, 0, stream>>>(Qf, Kf, logits, Ptp);
  finalize<<<dim3(32, 8), 256, 0, stream>>>(Ptp, Vbf, out);
}

// Round 11
// 158.781 us; speedup vs baseline: 1.0372x; 1.0372x over previous
//
#include <hip/hip_runtime.h>
#include <hip/hip_bf16.h>
#include <math.h>

#define NEGV (-1e10f)

typedef __attribute__((ext_vector_type(8))) short bf16x8;
typedef __attribute__((ext_vector_type(4))) float f32x4;
typedef __attribute__((ext_vector_type(16))) float f32x16;

static __device__ __forceinline__ unsigned short f2bf(float f) {
  unsigned int u = __builtin_bit_cast(unsigned int, f);
  unsigned int r = (u + 0x7fffu + ((u >> 16) & 1u)) >> 16;
  return (unsigned short)r;
}
static __device__ __forceinline__ float bf2f(unsigned short v) {
  return __builtin_bit_cast(float, (unsigned int)v << 16);
}
// RNE pack of two f32 -> two bf16 in one u32 (identical rounding to f2bf)
static __device__ __forceinline__ unsigned int pkbf(float lo, float hi) {
  unsigned int r;
  asm("v_cvt_pk_bf16_f32 %0, %1, %2" : "=v"(r) : "v"(lo), "v"(hi));
  return r;
}

#define GLD16(g, l)                                                   \
  __builtin_amdgcn_global_load_lds(                                   \
      (const __attribute__((address_space(1))) void*)(g),             \
      (__attribute__((address_space(3))) void*)(l), 16, 0, 0)

// ---------------------------------------------------------------------------
// K1: merged input casts + out-zeroing (replaces hipMemsetAsync launch).
// Blocks [0,2048): emb fp32->bf16 + attn-weight logits. Blocks [2048,3776):
// weight matrices fp32->bf16; W_q is PRE-SCALED by C2 = log2e/sqrt(96) in
// fp32 (folds the attn softmax scale into the GEMM; QK^T then feeds exp2
// directly). W_q/W_k rows are PERMUTED (same perm on both -> QK^T invariant).
// ---------------------------------------------------------------------------
__global__ __launch_bounds__(256) void cast_inputs(
    const float* __restrict__ emb, const int* __restrict__ tags,
    const float* __restrict__ ww, const float* __restrict__ wq,
    const float* __restrict__ wk, const float* __restrict__ wv,
    unsigned short* __restrict__ embbf, float* __restrict__ logits,
    unsigned short* __restrict__ wbf, float* __restrict__ out) {
  int bx = blockIdx.x;
  if (bx < 2048) {
    int w = threadIdx.x >> 6, lane = threadIdx.x & 63;
    int row = bx * 4 + w;  // 0..8191
    const float4* src = (const float4*)(emb + (size_t)row * 768);
    const float4* wsrc = (const float4*)ww;
    uint2* dst = (uint2*)(embbf + (size_t)row * 768);
    float d = 0.f;
#pragma unroll
    for (int j = 0; j < 3; j++) {
      int idx = lane + 64 * j;
      float4 v = src[idx];
      float4 wv = wsrc[idx];
      d += v.x * wv.x + v.y * wv.y + v.z * wv.z + v.w * wv.w;
      uint2 o;
      o.x = pkbf(v.x, v.y);
      o.y = pkbf(v.z, v.w);
      dst[idx] = o;
    }
#pragma unroll
    for (int off = 32; off; off >>= 1) d += __shfl_xor(d, off);
    if (lane == 0) logits[row] = (tags[row] == 0) ? NEGV : d;
  } else {
    int g = bx - 2048;              // 0..1727
    int z = g / 576;                // matrix
    int idx = (g - z * 576) * 256 + threadIdx.x;  // float4 index
    const float* src = (z == 0) ? wq : (z == 1) ? wk : wv;
    float4 v = ((const float4*)src)[idx];
    if (z == 0) {  // fold softmax scale into W_q (fp32, before bf16 round)
      const float C2 = 0.10206207261596577f * 1.4426950408889634f;
      v.x *= C2; v.y *= C2; v.z *= C2; v.w *= C2;
    }
    uint2 o;
    o.x = pkbf(v.x, v.y);
    o.y = pkbf(v.z, v.w);
    uint2* W2 = (uint2*)(wbf + (size_t)z * 589824);
    if (z == 2) {
      W2[idx] = o;
    } else {
      int f = idx / 192;            // source feature row
      int col4 = idx - f * 192;
      int h = f & 7, dg = f >> 3;   // head, depth 0..95
      int tt = dg >> 4, ddl = dg & 15;
      int wn = ddl >> 3, cb = (ddl >> 2) & 1, j = ddl & 3;
      int orow = tt * 128 + wn * 64 + j * 16 + cb * 8 + h;
      W2[orow * 192 + col4] = o;
    }
    if (bx == 3775) {  // zero `out` (8x768 f32 = 1536 float4); stream order
      float4 z4 = {0.f, 0.f, 0.f, 0.f};  // guarantees this precedes finalize
#pragma unroll
      for (int q = 0; q < 6; q++) ((float4*)out)[q * 256 + threadIdx.x] = z4;
    }
  }
}

// ---------------------------------------------------------------------------
// K3: QKV projection GEMM, v6 (R7/R8-verified best): XCD-chunked block remap
// (T1), 3-buffer LDS ring, depth-2 prefetch, counted vmcnt(4)+raw barrier,
// conflict-free fragment swizzle. Grid LINEAR 1152 = 8 XCDs x 144;
// xcd = g&7 owns mb-panels [xcd*8, xcd*8+8) == batch xcd -> A-panels (1.5MB)
// + one B matrix (1.18MB) L2-resident per XCD. See R3/R5/R6 comments.
// History: 53.2 (R0) -> 44.4 (ring+occupancy) -> conflict-free swizzle
// (3.59M -> 49K) -> XCD remap (FETCH 26 -> 21MB). Further pipeline attempts
// (reg-B dbuf R1; setprio R4) regressed — this is the structure's ceiling.
// ---------------------------------------------------------------------------
__global__ __launch_bounds__(256, 3) void qkv_gemm(
    const unsigned short* __restrict__ A, const unsigned short* __restrict__ Wbf,
    unsigned short* __restrict__ Qf, unsigned short* __restrict__ Kf,
    unsigned short* __restrict__ Vbf) {
  __shared__ __align__(16) unsigned short sm[24576];  // ring: 3 x 8192 shorts
  int g = blockIdx.x;          // 0..1151
  int xcd = g & 7, local = g >> 3;
  int mbi = xcd * 8 + (local & 7);  // 0..63
  int nbz = local >> 3;             // 0..17
  int z = nbz / 6;
  int nbi = nbz - z * 6;            // 0..5
  const unsigned short* B = Wbf + (size_t)z * 589824;
  int mb = mbi * 128, nb = nbi * 128;
  int tid = threadIdx.x;
  int w = tid >> 6, lane = tid & 63;
  int wm = w >> 1, wn = w & 1;
  int c = lane & 15, quad = lane >> 4;
  int lrow = lane >> 2;
  int lcol = ((lane & 3) ^ ((lrow >> 1) & 3)) * 8;  // bank-spread source chunk
  const unsigned short* Ag = A + (size_t)(mb + w * 32 + lrow) * 768 + lcol;
  const unsigned short* Bg = B + (size_t)(nb + w * 32 + lrow) * 768 + lcol;
  int woff = w * 1024;

  // One K-tile stage: A -> slot base, B -> slot base + 4096 (shorts)
#define PREFETCH(buf, kb)                                                   \
  do {                                                                      \
    GLD16(Ag + (kb), sm + (buf) * 8192 + woff);                             \
    GLD16(Ag + (kb) + 16 * 768, sm + (buf) * 8192 + woff + 512);            \
    GLD16(Bg + (kb), sm + (buf) * 8192 + 4096 + woff);                      \
    GLD16(Bg + (kb) + 16 * 768, sm + (buf) * 8192 + 4096 + woff + 512);     \
  } while (0)

  f32x4 acc[4][4];
#pragma unroll
  for (int i = 0; i < 4; i++)
#pragma unroll
    for (int j = 0; j < 4; j++) acc[i][j] = 0;

  PREFETCH(0, 0);
  PREFETCH(1, 32);

  int rd = 0;
  int sw = (quad ^ ((c >> 1) & 3)) * 8;  // conflict-free swizzled chunk
  for (int it = 0; it < 24; it++) {
    if (it < 23) {
      asm volatile("s_waitcnt vmcnt(4) lgkmcnt(0)" ::: "memory");
    } else {
      asm volatile("s_waitcnt vmcnt(0) lgkmcnt(0)" ::: "memory");
    }
    __builtin_amdgcn_s_barrier();
    if (it + 2 < 24) {
      int wr = rd + 2;
      if (wr >= 3) wr -= 3;
      PREFETCH(wr, (it + 2) * 32);
    }
    const unsigned short* Ab = sm + rd * 8192;
    const unsigned short* Bb = Ab + 4096;
    bf16x8 af[4], bfr[4];
#pragma unroll
    for (int i = 0; i < 4; i++)
      af[i] = *(const bf16x8*)&Ab[(wm * 64 + i * 16 + c) * 32 + sw];
#pragma unroll
    for (int j = 0; j < 4; j++)
      bfr[j] = *(const bf16x8*)&Bb[(wn * 64 + j * 16 + c) * 32 + sw];
#pragma unroll
    for (int i = 0; i < 4; i++)
#pragma unroll
      for (int j = 0; j < 4; j++)
        acc[i][j] = __builtin_amdgcn_mfma_f32_16x16x32_bf16(af[i], bfr[j],
                                                            acc[i][j], 0, 0, 0);
    rd = (rd == 2) ? 0 : rd + 1;
  }
  __syncthreads();  // all staging/reads done before epilogue reuses sm

  // C row = mb+wm*64+i*16+quad*4+r, col = nb+wn*64+j*16+c
  if (z == 2) {
#pragma unroll
    for (int i = 0; i < 4; i++)
#pragma unroll
      for (int j = 0; j < 4; j++)
#pragma unroll
        for (int r = 0; r < 4; r++) {
          int rl = wm * 64 + i * 16 + quad * 4 + r;
          int cl = wn * 64 + j * 16 + c;
          sm[rl * 136 + cl] = f2bf(acc[i][j][r]);
        }
    __syncthreads();
#pragma unroll
    for (int it2 = 0; it2 < 8; it2++) {
      int g2 = it2 * 256 + tid;  // 0..2047, 16B units (128 rows x 16)
      int rl = g2 >> 4;
      int cu = (g2 & 15) * 8;
      bf16x8 vdat = *(const bf16x8*)&sm[rl * 136 + cu];
      *(bf16x8*)&Vbf[(size_t)(mb + rl) * 768 + nb + cu] = vdat;
    }
  } else {
    unsigned short* O = (z == 0) ? Qf : Kf;
#pragma unroll
    for (int i = 0; i < 4; i++) {
#pragma unroll
      for (int r = 0; r < 4; r++) {
        int qlr = wm * 64 + i * 16 + quad * 4 + r;  // 0..127
        int chunkL = (qlr >> 5) * 8 + (c & 7);      // 0..31
        int lane32 = (qlr & 31) + wn * 32;
        uint2 o;
        o.x = pkbf(acc[i][0][r], acc[i][1][r]);
        o.y = pkbf(acc[i][2][r], acc[i][3][r]);
        *(uint2*)&sm[chunkL * 520 + lane32 * 8 + 4 * (c >> 3)] = o;
      }
    }
    __syncthreads();
    int bq = mb >> 10;
    int qt32g0 = (mb & 1023) >> 5;
    int tt = nbi;  // d/16 chunk (0..5)
#pragma unroll
    for (int it2 = 0; it2 < 8; it2++) {
      int gg = it2 * 256 + tid;
      int chunkL = gg >> 6;
      int off = (gg & 63) * 8;
      bf16x8 vdat = *(const bf16x8*)&sm[chunkL * 520 + off];
      int qt32 = qt32g0 + (chunkL >> 3), h = chunkL & 7;
      size_t dst = ((((size_t)(bq * 32 + qt32) * 8 + h) * 6 + tt) << 9) + off;
      *(bf16x8*)&O[dst] = vdat;
    }
  }
#undef PREFETCH
}

// ---------------------------------------------------------------------------
// K4: attention, R8-EXACT (best verified config, total 160.65us).
// Barrier-free direct global->VGPR fragment loads + inline aw-softmax
// prologue + pre-scaled W_q (epilogue exp2 directly). LDS staging of Q/K
// was tried twice and refuted: depth-1 dbuf (R6, +7us) and ring-3 with
// counted vmcnt (R10, +4us) — the compiler-hoisted independent loads beat
// any barrier-structured pipeline for this shape (all data L2-resident,
// short 6-MFMA phases < L2 latency). Structural bounds: acc[8] f32x16 =
// 128 AGPR caps occupancy at 8 waves/CU; 67M v_exp_f32 (h-softmax quirk)
// is algorithm-mandated VALU floor.
// Grid: 2048 linear; b = id&7 pins batch b to XCD b (qkv wrote it there).
// ---------------------------------------------------------------------------
__global__ __launch_bounds__(256) void attn(
    const unsigned short* __restrict__ Qf, const unsigned short* __restrict__ Kf,
    const float* __restrict__ logits, float* __restrict__ Ptp) {
  __shared__ float pbuf[1024];  // aw[q] in prologue; partials in epilogue
  __shared__ float red[4];
  int id = blockIdx.x;
  int b = id & 7, qb = (id >> 3) & 15, kb = id >> 7;
  int tid = threadIdx.x, w = tid >> 6, lane = tid & 63;
  int wq = w >> 1, wk = w & 1;
  const unsigned short* Qb =
      Qf + ((size_t)(b * 32 + qb * 2 + wq) * 48) * 512 + (size_t)lane * 8;
  const unsigned short* Kb =
      Kf + ((size_t)(b * 32 + kb * 2 + wk) * 48) * 512 + (size_t)lane * 8;

  // preload h=0 fragments: in flight during the softmax prologue
  bf16x8 qa[6], ka[6];
#pragma unroll
  for (int t = 0; t < 6; t++) {
    qa[t] = *(const bf16x8*)(Qb + (size_t)t * 512);
    ka[t] = *(const bf16x8*)(Kb + (size_t)t * 512);
  }

  {  // inline softmax of masked logits -> pbuf[q] = aw (q = 0..1023)
    const float* L = logits + b * 1024;
    float x0 = L[tid], x1 = L[tid + 256], x2 = L[tid + 512], x3 = L[tid + 768];
    float m = fmaxf(fmaxf(x0, x1), fmaxf(x2, x3));
#pragma unroll
    for (int off = 32; off; off >>= 1) m = fmaxf(m, __shfl_xor(m, off));
    if ((tid & 63) == 0) red[tid >> 6] = m;
    __syncthreads();
    m = fmaxf(fmaxf(red[0], red[1]), fmaxf(red[2], red[3]));
    float e0 = __expf(x0 - m), e1 = __expf(x1 - m), e2 = __expf(x2 - m),
          e3 = __expf(x3 - m);
    float s = e0 + e1 + e2 + e3;
#pragma unroll
    for (int off = 32; off; off >>= 1) s += __shfl_xor(s, off);
    __syncthreads();  // red WAR guard
    if ((tid & 63) == 0) red[tid >> 6] = s;
    __syncthreads();
    float inv = 1.0f / (red[0] + red[1] + red[2] + red[3]);
    pbuf[tid] = e0 * inv;
    pbuf[tid + 256] = e1 * inv;
    pbuf[tid + 512] = e2 * inv;
    pbuf[tid + 768] = e3 * inv;
    __syncthreads();
  }

  f32x16 acc[8];
#pragma unroll
  for (int h = 0; h < 8; h++) acc[h] = 0;
#pragma unroll
  for (int h = 0; h < 8; h++) {
#pragma unroll
    for (int t = 0; t < 6; t++) {
      bf16x8 a = (h == 0) ? qa[t] : *(const bf16x8*)(Qb + (size_t)(h * 6 + t) * 512);
      bf16x8 bb = (h == 0) ? ka[t] : *(const bf16x8*)(Kb + (size_t)(h * 6 + t) * 512);
      acc[h] = __builtin_amdgcn_mfma_f32_32x32x16_bf16(a, bb, acc[h], 0, 0, 0);
    }
  }

  // softmax over h per (q,k); C/D: col=lane&31 (k), row=(reg&3)+8*(reg>>2)+4*(lane>>5)
  float awv[16];
#pragma unroll
  for (int reg = 0; reg < 16; reg++) {
    int row = (reg & 3) + 8 * (reg >> 2) + 4 * (lane >> 5);
    awv[reg] = pbuf[qb * 64 + wq * 32 + row];
  }
  __syncthreads();  // all aw reads done before pbuf is overwritten below
  float partial[8];
#pragma unroll
  for (int h = 0; h < 8; h++) partial[h] = 0.f;
#pragma unroll
  for (int reg = 0; reg < 16; reg++) {
    float v[8];
    float ssum = 0.f;
#pragma unroll
    for (int h = 0; h < 8; h++) {
      float e = exp2f(acc[h][reg]);  // scale pre-folded into W_q
      v[h] = e;
      ssum += e;
    }
    float g = awv[reg] * __builtin_amdgcn_rcpf(ssum);  // aw==0 for padded q
#pragma unroll
    for (int h = 0; h < 8; h++) partial[h] += v[h] * g;
  }
#pragma unroll
  for (int h = 0; h < 8; h++) {
    float v = partial[h];
    v += __shfl_xor(v, 32);  // combine row halves -> full 32-q sum per col
    partial[h] = v;
  }
  if (lane < 32) {
#pragma unroll
    for (int h = 0; h < 8; h++) pbuf[w * 256 + lane * 8 + h] = partial[h];
  }
  __syncthreads();
  // 256 threads each write BOTH wk halves (512 outputs total)
#pragma unroll
  for (int wk2 = 0; wk2 < 2; wk2++) {
    float s = pbuf[wk2 * 256 + tid] + pbuf[(2 + wk2) * 256 + tid];
    int kcol = tid >> 3, h = tid & 7;
    Ptp[(((size_t)qb * 8 + b) * 1024 + kb * 64 + wk2 * 32 + kcol) * 8 + h] = s;
  }
}

// ---------------------------------------------------------------------------
// K5: out[b,o] = sum_k (sum_qb Ptp[qb][b][k][o&7]) * V[b,k,o]   (V bf16)
// grid (32 kc, 8 b); threads 0..191 each own 4 consecutive o (ushort4 loads)
// out zeroed by cast_inputs (stream-ordered).
// ---------------------------------------------------------------------------
__global__ __launch_bounds__(256) void finalize(
    const float* __restrict__ Ptp, const unsigned short* __restrict__ Vbf,
    float* __restrict__ out) {
  __shared__ float ps[256];  // 32 k x 8 h
  int kc = blockIdx.x, b = blockIdx.y;
  int t = threadIdx.x;
  {
    int k = kc * 32 + (t >> 3), h = t & 7;
    float s = 0.f;
#pragma unroll
    for (int qc = 0; qc < 16; qc++)
      s += Ptp[(((size_t)qc * 8 + b) * 1024 + k) * 8 + h];
    ps[t] = s;
  }
  __syncthreads();
  if (t < 192) {
    int o0 = t * 4;
    int hb = o0 & 7;  // 0 or 4
    float a0 = 0, a1 = 0, a2 = 0, a3 = 0;
    const unsigned short* Vb = Vbf + ((size_t)b * 1024 + kc * 32) * 768 + o0;
#pragma unroll 4
    for (int kk = 0; kk < 32; kk++) {
      ushort4 vv = *(const ushort4*)(Vb + (size_t)kk * 768);
      const float* p = &ps[kk * 8 + hb];
      a0 += p[0] * bf2f(vv.x);
      a1 += p[1] * bf2f(vv.y);
      a2 += p[2] * bf2f(vv.z);
      a3 += p[3] * bf2f(vv.w);
    }
    atomicAdd(&out[b * 768 + o0], a0);
    atomicAdd(&out[b * 768 + o0 + 1], a1);
    atomicAdd(&out[b * 768 + o0 + 2], a2);
    atomicAdd(&out[b * 768 + o0 + 3], a3);
  }
}

// ---------------------------------------------------------------------------
extern "C" void kernel_launch(void* const* d_in, const int* in_sizes, int n_in,
                              void* d_out, int out_size, void* d_ws,
                              size_t ws_size, hipStream_t stream) {
  const float* emb = (const float*)d_in[0];
  const int* tags = (const int*)d_in[1];
  const float* ww = (const float*)d_in[2];
  const float* wq = (const float*)d_in[3];
  const float* wk = (const float*)d_in[4];
  const float* wv = (const float*)d_in[5];
  float* out = (float*)d_out;
  char* ws = (char*)d_ws;
  unsigned short* embbf = (unsigned short*)(ws + 0);           // 12,582,912
  unsigned short* wbf   = (unsigned short*)(ws + 12582912);    //  3,538,944
  unsigned short* Qf    = (unsigned short*)(ws + 16121856);    // 12,582,912
  unsigned short* Kf    = (unsigned short*)(ws + 28704768);    // 12,582,912
  unsigned short* Vbf   = (unsigned short*)(ws + 41287680);    // 12,582,912
  float* logits         = (float*)(ws + 53870592);             //     32,768
  float* Ptp            = (float*)(ws + 53936128);             //  4,194,304

  cast_inputs<<<3776, 256, 0, stream>>>(emb, tags, ww, wq, wk, wv, embbf,
                                        logits, wbf, out);
  qkv_gemm<<<1152, 256, 0, stream>>>(embbf, wbf, Qf, Kf, Vbf);
  attn<<<2048, 256, 0, stream>>>(Qf, Kf, logits, Ptp);
  finalize<<<dim3(32, 8), 256, 0, stream>>>(Ptp, Vbf, out);
}